// Round 2
// baseline (6705.071 us; speedup 1.0000x reference)
//
#include <hip/hip_runtime.h>
#include <hip/hip_bf16.h>

#define B_ 64
#define T_ 256
#define EMB_ 512
#define HID_ 1024
#define G4_ 4096
#define NCLS_ 32000
#define WSTRIDE 1032  // 1024 + 8 f16 pad: 2064B row stride -> lanes hit 4-bank offsets, 2-way max (free)

typedef _Float16 f16;
typedef _Float16 f16x8 __attribute__((ext_vector_type(8)));
typedef _Float16 f16x4 __attribute__((ext_vector_type(4)));
typedef float f32x4 __attribute__((ext_vector_type(4)));

__device__ __forceinline__ float sigm(float x) { return 1.f / (1.f + __expf(-x)); }

// ---------------- prep kernels ----------------

__global__ __launch_bounds__(256) void cvt_kernel(const float* __restrict__ src,
                                                  f16* __restrict__ dst, int n4) {
  int i = blockIdx.x * 256 + threadIdx.x;
  if (i < n4) {
    float4 v = ((const float4*)src)[i];
    f16x4 o = {(f16)v.x, (f16)v.y, (f16)v.z, (f16)v.w};
    *(f16x4*)(dst + (size_t)i * 4) = o;
  }
}

__global__ __launch_bounds__(256) void bsum_kernel(const float* __restrict__ a0,
                                                   const float* __restrict__ b0,
                                                   float* __restrict__ o0,
                                                   const float* __restrict__ a1,
                                                   const float* __restrict__ b1,
                                                   float* __restrict__ o1) {
  int i = blockIdx.x * 256 + threadIdx.x;
  if (i < G4_) {
    o0[i] = a0[i] + b0[i];
    o1[i] = a1[i] + b1[i];
  }
}

// x0 layout: [T][B][EMB] fp16
__global__ __launch_bounds__(128) void gather_kernel(const int* __restrict__ tokens,
                                                     const float* __restrict__ emb,
                                                     f16* __restrict__ x0) {
  int blk = blockIdx.x;  // t*64 + b
  int t = blk >> 6, b = blk & 63;
  int tok = tokens[b * T_ + t];
  float4 v = ((const float4*)(emb + (size_t)tok * EMB_))[threadIdx.x];
  f16x4 o = {(f16)v.x, (f16)v.y, (f16)v.z, (f16)v.w};
  *(f16x4*)(x0 + (size_t)blk * EMB_ + threadIdx.x * 4) = o;
}

// ---------------- persistent pipelined recurrence kernel ----------------
// grid = 256 blocks (1/CU, LDS-limited), 4 stages x 64 slices:
//   stage 0 (blocks   0..63): rec0  t=s-1   W_hh0 slice resident in LDS
//   stage 1 (blocks  64..127): rec1 t=s-3   W_hh1 slice
//   stage 2 (blocks 128..191): xg1  t=s-2   W_ih1 slice
//   stage 3 (blocks 192..255): xg0  t=s     W_ih0 slice (K=512)
// One monotonic-counter grid barrier per step (agent-scope release/acquire).
__global__ __launch_bounds__(256, 1) void persist_kernel(
    const f16* __restrict__ x0, const f16* __restrict__ w0i,
    const f16* __restrict__ w0h, const f16* __restrict__ w1i,
    const f16* __restrict__ w1h, const float* __restrict__ b0s,
    const float* __restrict__ b1s, float* __restrict__ xg0,
    float* __restrict__ xg1, f16* __restrict__ h0r, f16* __restrict__ h1r,
    unsigned* ctr) {
  __shared__ f16 Ws[64 * WSTRIDE];   // 129.0 KB weight slice
  __shared__ float pre[64 * 68];     // 17.4 KB preact exchange (rec)
  __shared__ float cst[64 * 16];     // 4 KB cell state (rec)

  const int stage = blockIdx.x >> 6;
  const int slice = blockIdx.x & 63;
  const int tid = threadIdx.x;
  const int lane = tid & 63, wave = tid >> 6;
  const int wm = wave & 1, wn = wave >> 1;
  const int lr = lane & 15, lk = lane >> 4;
  const int j0 = slice * 16;
  const bool isrec = (stage <= 1);
  const int K = (stage == 3) ? EMB_ : HID_;

  // ---- preload weight slice into LDS (once) ----
  {
    const f16* Wg = (stage == 0) ? w0h : (stage == 1) ? w1h : (stage == 2) ? w1i : w0i;
    const int shf = (stage == 3) ? 6 : 7;       // 16B chunks per row = K/8
    const int nchunk = 64 << shf;
    for (int i = tid; i < nchunk; i += 256) {
      int r = i >> shf, c8 = i & ((1 << shf) - 1);
      int brow = isrec ? ((r >> 4) * HID_ + j0 + (r & 15)) : (slice * 64 + r);
      uint4 v = *(const uint4*)(Wg + (size_t)brow * K + c8 * 8);
      *(uint4*)(Ws + r * WSTRIDE + c8 * 8) = v;
    }
    for (int i = tid; i < 1024; i += 256) cst[i] = 0.f;
  }
  __syncthreads();

  // hoisted fragment base addresses
  f16* Brow0 = Ws + (wn * 32 + lr) * WSTRIDE + lk * 8;
  f16* Brow1 = Brow0 + 16 * WSTRIDE;

  int deadL = 0;
  for (int s = 0; s < T_ + 3; ++s) {
    bool active;
    const f16* A;
    if (stage == 0) { active = (s >= 1 && s <= 256); A = h0r + ((s - 2) & 1) * (B_ * HID_); }
    else if (stage == 1) { active = (s >= 3); A = h1r + ((s - 4) & 1) * (B_ * HID_); }
    else if (stage == 2) { active = (s >= 2 && s <= 257); A = h0r + ((s - 2) & 1) * (B_ * HID_); }
    else { active = (s <= 255); A = x0 + (size_t)s * (B_ * EMB_); }

    if (active) {
      f32x4 acc[2][2] = {};
      const f16* Arow0 = A + (wm * 32 + lr) * K + lk * 8;
      const f16* Arow1 = Arow0 + 16 * K;
      const int nks = K >> 5;
#pragma unroll 8
      for (int ks = 0; ks < nks; ++ks) {
        f16x8 a0 = *(const f16x8*)(Arow0 + ks * 32);
        f16x8 a1 = *(const f16x8*)(Arow1 + ks * 32);
        f16x8 b0 = *(const f16x8*)(Brow0 + ks * 32);
        f16x8 b1 = *(const f16x8*)(Brow1 + ks * 32);
        acc[0][0] = __builtin_amdgcn_mfma_f32_16x16x32_f16(a0, b0, acc[0][0], 0, 0, 0);
        acc[0][1] = __builtin_amdgcn_mfma_f32_16x16x32_f16(a0, b1, acc[0][1], 0, 0, 0);
        acc[1][0] = __builtin_amdgcn_mfma_f32_16x16x32_f16(a1, b0, acc[1][0], 0, 0, 0);
        acc[1][1] = __builtin_amdgcn_mfma_f32_16x16x32_f16(a1, b1, acc[1][1], 0, 0, 0);
      }

      if (!isrec) {
        float* out = (stage == 2) ? xg1 + ((s - 2) & 1) * (B_ * G4_)
                                  : xg0 + (s & 1) * (B_ * G4_);
        const float* bs = (stage == 2) ? b1s : b0s;
#pragma unroll
        for (int mf = 0; mf < 2; ++mf)
#pragma unroll
          for (int nf = 0; nf < 2; ++nf) {
            int n = slice * 64 + wn * 32 + nf * 16 + lr;
            float bias = bs[n];
            int bbase = wm * 32 + mf * 16 + lk * 4;
#pragma unroll
            for (int rg = 0; rg < 4; ++rg)
              out[(bbase + rg) * G4_ + n] = acc[mf][nf][rg] + bias;
          }
      } else {
        // exchange preacts through LDS so each thread sees all 4 gates
#pragma unroll
        for (int mf = 0; mf < 2; ++mf)
#pragma unroll
          for (int nf = 0; nf < 2; ++nf) {
            int nl = wn * 32 + nf * 16 + lr;
            int bl = wm * 32 + mf * 16 + lk * 4;
            *(f32x4*)(pre + nl * 68 + bl) = acc[mf][nf];
          }
        __syncthreads();
        const float* xg;
        f16* hout;
        if (stage == 0) {
          xg = xg0 + ((s - 1) & 1) * (B_ * G4_);
          hout = h0r + ((s - 1) & 1) * (B_ * HID_);
        } else {
          xg = xg1 + ((s - 3) & 1) * (B_ * G4_);
          hout = h1r + ((s - 3) & 1) * (B_ * HID_);
        }
#pragma unroll
        for (int i = 0; i < 4; ++i) {
          int id = tid + 256 * i;  // 0..1023
          int u = id & 15, b = id >> 4;
          int j = j0 + u;
          float pi = pre[u * 68 + b]        + xg[b * G4_ + j];
          float pf = pre[(16 + u) * 68 + b] + xg[b * G4_ + HID_ + j];
          float pg = pre[(32 + u) * 68 + b] + xg[b * G4_ + 2 * HID_ + j];
          float po = pre[(48 + u) * 68 + b] + xg[b * G4_ + 3 * HID_ + j];
          float ig = sigm(pi), fg = sigm(pf), gg = tanhf(pg), og = sigm(po);
          float cn = fg * cst[b * 16 + u] + ig * gg;
          cst[b * 16 + u] = cn;
          hout[b * HID_ + j] = (f16)(og * tanhf(cn));
        }
      }
    }

    // ---- grid barrier (monotonic counter, agent scope) ----
    if (s < T_ + 2) {
      __syncthreads();
      if (tid == 0) {
        __builtin_amdgcn_fence(__ATOMIC_RELEASE, "agent");
        __hip_atomic_fetch_add(ctr, 1u, __ATOMIC_RELAXED, __HIP_MEMORY_SCOPE_AGENT);
        if (!deadL) {
          const unsigned target = 256u * (unsigned)(s + 1);
          int spins = 0;
          while (__hip_atomic_load(ctr, __ATOMIC_RELAXED, __HIP_MEMORY_SCOPE_AGENT) < target) {
            __builtin_amdgcn_s_sleep(4);
            if (++spins > 2000000) { deadL = 1; break; }  // safety valve: degrade, don't hang
          }
        }
        __builtin_amdgcn_fence(__ATOMIC_ACQUIRE, "agent");
      }
      __syncthreads();
    }
  }
}

// ---------------- FC kernel: out = h1_last @ fc_w^T + fc_b ----------------
__global__ __launch_bounds__(256) void fc_kernel(const f16* __restrict__ A,
                                                 const float* __restrict__ fcw,
                                                 const float* __restrict__ fcb,
                                                 float* __restrict__ out) {
  const int n0 = blockIdx.x * 64;
  __shared__ char smem[18432];
  f16* As = (f16*)smem;
  f16* Bs = (f16*)(smem + 9216);
  const int tid = threadIdx.x;
  const int lane = tid & 63, wave = tid >> 6;
  const int wm = wave & 1, wn = wave >> 1;
  const int lr = lane & 15, lk = lane >> 4;
  f32x4 acc[2][2] = {};

  for (int kt = 0; kt < HID_ / 64; ++kt) {
    const int k0 = kt * 64;
    __syncthreads();
#pragma unroll
    for (int i = 0; i < 2; ++i) {
      int id = tid + 256 * i;
      int r = id >> 3, c8 = id & 7;
      uint4 av = *(const uint4*)(A + (size_t)r * HID_ + k0 + c8 * 8);
      *(uint4*)(As + r * 72 + c8 * 8) = av;
    }
#pragma unroll
    for (int i = 0; i < 4; ++i) {
      int id = tid + 256 * i;
      int r = id >> 4, c4 = id & 15;
      float4 v = *(const float4*)(fcw + (size_t)(n0 + r) * HID_ + k0 + c4 * 4);
      f16x4 o = {(f16)v.x, (f16)v.y, (f16)v.z, (f16)v.w};
      *(f16x4*)(Bs + r * 72 + c4 * 4) = o;
    }
    __syncthreads();
#pragma unroll
    for (int ks = 0; ks < 2; ++ks) {
      f16x8 a0 = *(const f16x8*)(As + (wm * 32 + lr) * 72 + ks * 32 + lk * 8);
      f16x8 a1 = *(const f16x8*)(As + (wm * 32 + 16 + lr) * 72 + ks * 32 + lk * 8);
      f16x8 b0 = *(const f16x8*)(Bs + (wn * 32 + lr) * 72 + ks * 32 + lk * 8);
      f16x8 b1 = *(const f16x8*)(Bs + (wn * 32 + 16 + lr) * 72 + ks * 32 + lk * 8);
      acc[0][0] = __builtin_amdgcn_mfma_f32_16x16x32_f16(a0, b0, acc[0][0], 0, 0, 0);
      acc[0][1] = __builtin_amdgcn_mfma_f32_16x16x32_f16(a0, b1, acc[0][1], 0, 0, 0);
      acc[1][0] = __builtin_amdgcn_mfma_f32_16x16x32_f16(a1, b0, acc[1][0], 0, 0, 0);
      acc[1][1] = __builtin_amdgcn_mfma_f32_16x16x32_f16(a1, b1, acc[1][1], 0, 0, 0);
    }
  }

#pragma unroll
  for (int mf = 0; mf < 2; ++mf)
#pragma unroll
    for (int nf = 0; nf < 2; ++nf) {
      int n = n0 + wn * 32 + nf * 16 + lr;
      float bias = fcb[n];
      int bbase = wm * 32 + mf * 16 + lk * 4;
#pragma unroll
      for (int rg = 0; rg < 4; ++rg)
        out[(size_t)(bbase + rg) * NCLS_ + n] = acc[mf][nf][rg] + bias;
    }
}

// ---------------- launch ----------------

extern "C" void kernel_launch(void* const* d_in, const int* in_sizes, int n_in,
                              void* d_out, int out_size, void* d_ws,
                              size_t ws_size, hipStream_t stream) {
  const int* tokens = (const int*)d_in[0];
  const float* emb = (const float*)d_in[1];
  const float* W_ih0 = (const float*)d_in[2];
  const float* W_hh0 = (const float*)d_in[3];
  const float* b_ih0 = (const float*)d_in[4];
  const float* b_hh0 = (const float*)d_in[5];
  const float* W_ih1 = (const float*)d_in[6];
  const float* W_hh1 = (const float*)d_in[7];
  const float* b_ih1 = (const float*)d_in[8];
  const float* b_hh1 = (const float*)d_in[9];
  const float* fc_w = (const float*)d_in[10];
  const float* fc_b = (const float*)d_in[11];
  float* out = (float*)d_out;

  char* ws = (char*)d_ws;
  size_t off = 0;
  auto carve = [&](size_t bytes) -> char* {
    char* p = ws + off;
    off += (bytes + 255) & ~(size_t)255;
    return p;
  };
  f16* w0i = (f16*)carve((size_t)G4_ * EMB_ * 2);
  f16* w0h = (f16*)carve((size_t)G4_ * HID_ * 2);
  f16* w1i = (f16*)carve((size_t)G4_ * HID_ * 2);
  f16* w1h = (f16*)carve((size_t)G4_ * HID_ * 2);
  f16* x0 = (f16*)carve((size_t)T_ * B_ * EMB_ * 2);
  float* b0s = (float*)carve(G4_ * 4);
  float* b1s = (float*)carve(G4_ * 4);
  float* xg0 = (float*)carve(2ull * B_ * G4_ * 4);
  float* xg1 = (float*)carve(2ull * B_ * G4_ * 4);
  const size_t state_bytes = 4ull * B_ * HID_ * 2 + 256;  // h0 ring (2), h1 ring (2), ctr
  char* state = carve(state_bytes);
  f16* h0r = (f16*)state;
  f16* h1r = (f16*)(state + 2 * B_ * HID_ * 2);
  unsigned* ctr = (unsigned*)(state + 4 * B_ * HID_ * 2);

  // zero h rings + barrier counter (every call: deterministic)
  hipMemsetAsync(state, 0, state_bytes, stream);

  cvt_kernel<<<(G4_ * EMB_ / 4 + 255) / 256, 256, 0, stream>>>(W_ih0, w0i, G4_ * EMB_ / 4);
  cvt_kernel<<<(G4_ * HID_ / 4 + 255) / 256, 256, 0, stream>>>(W_hh0, w0h, G4_ * HID_ / 4);
  cvt_kernel<<<(G4_ * HID_ / 4 + 255) / 256, 256, 0, stream>>>(W_ih1, w1i, G4_ * HID_ / 4);
  cvt_kernel<<<(G4_ * HID_ / 4 + 255) / 256, 256, 0, stream>>>(W_hh1, w1h, G4_ * HID_ / 4);
  bsum_kernel<<<(G4_ + 255) / 256, 256, 0, stream>>>(b_ih0, b_hh0, b0s, b_ih1, b_hh1, b1s);
  gather_kernel<<<T_ * B_, 128, 0, stream>>>(tokens, emb, x0);

  persist_kernel<<<256, 256, 0, stream>>>(x0, w0i, w0h, w1i, w1h, b0s, b1s,
                                          xg0, xg1, h0r, h1r, ctr);

  fc_kernel<<<NCLS_ / 64, 256, 0, stream>>>(h1r + B_ * HID_, fc_w, fc_b, out);
}

// Round 3
// 3713.660 us; speedup vs baseline: 1.8055x; 1.8055x over previous
//
#include <hip/hip_runtime.h>
#include <hip/hip_bf16.h>

#define B_ 64
#define T_ 256
#define EMB_ 512
#define HID_ 1024
#define G4_ 4096
#define NCLS_ 32000
#define BH (B_ * HID_)
#define BG4 (B_ * G4_)

typedef _Float16 f16;
typedef _Float16 f16x8 __attribute__((ext_vector_type(8)));
typedef _Float16 f16x4 __attribute__((ext_vector_type(4)));
typedef _Float16 f16x2 __attribute__((ext_vector_type(2)));
typedef float f32x4 __attribute__((ext_vector_type(4)));

__device__ __forceinline__ float sigm(float x) { return 1.f / (1.f + __expf(-x)); }

// ---- LLC-coherent (cross-XCD) accessors: relaxed agent-scope atomics bypass
// ---- the non-coherent per-XCD L2 and hit the shared Infinity Cache. NO fences.
__device__ __forceinline__ void stg_f32(float* p, float v) {
  __hip_atomic_store((unsigned*)p, __builtin_bit_cast(unsigned, v),
                     __ATOMIC_RELAXED, __HIP_MEMORY_SCOPE_AGENT);
}
__device__ __forceinline__ void stg_u32(unsigned* p, unsigned v) {
  __hip_atomic_store(p, v, __ATOMIC_RELAXED, __HIP_MEMORY_SCOPE_AGENT);
}
__device__ __forceinline__ unsigned long long ldg_u64(const void* p) {
  return __hip_atomic_load((const unsigned long long*)p, __ATOMIC_RELAXED,
                           __HIP_MEMORY_SCOPE_AGENT);
}

// ---------------- prep kernels ----------------

__global__ __launch_bounds__(256) void cvt_kernel(const float* __restrict__ src,
                                                  f16* __restrict__ dst, int n4) {
  int i = blockIdx.x * 256 + threadIdx.x;
  if (i < n4) {
    float4 v = ((const float4*)src)[i];
    f16x4 o = {(f16)v.x, (f16)v.y, (f16)v.z, (f16)v.w};
    *(f16x4*)(dst + (size_t)i * 4) = o;
  }
}

__global__ __launch_bounds__(256) void bsum_kernel(const float* __restrict__ a0,
                                                   const float* __restrict__ b0,
                                                   float* __restrict__ o0,
                                                   const float* __restrict__ a1,
                                                   const float* __restrict__ b1,
                                                   float* __restrict__ o1) {
  int i = blockIdx.x * 256 + threadIdx.x;
  if (i < G4_) {
    o0[i] = a0[i] + b0[i];
    o1[i] = a1[i] + b1[i];
  }
}

// x0 layout: [T][B][EMB] fp16
__global__ __launch_bounds__(128) void gather_kernel(const int* __restrict__ tokens,
                                                     const float* __restrict__ emb,
                                                     f16* __restrict__ x0) {
  int blk = blockIdx.x;  // t*64 + b
  int t = blk >> 6, b = blk & 63;
  int tok = tokens[b * T_ + t];
  float4 v = ((const float4*)(emb + (size_t)tok * EMB_))[threadIdx.x];
  f16x4 o = {(f16)v.x, (f16)v.y, (f16)v.z, (f16)v.w};
  *(f16x4*)(x0 + (size_t)blk * EMB_ + threadIdx.x * 4) = o;
}

// ---------------- persistent recurrence kernel ----------------
// grid = 256 blocks x 512 threads (8 waves: wm[2] x wn[2] x kh[2] K-split).
// Weights live in 128 VGPRs/lane for the whole kernel (weight-stationary).
// stage 0: rec0 t=s-1 | stage 1: rec1 t=s-3 | stage 2: xg1 t=s-2 | stage 3: xg0 t=s
// h rings: depth-257 single-assignment (normal cached loads OK).
// xg rings: depth-2, atomic store/load (LLC) both sides.
// Barrier: flag[bid]=steps_done (atomic store) + all-scan (atomic loads).

#define KLOOP(NKS)                                                                       \
  _Pragma("unroll") for (int f = 0; f < NKS; ++f) {                                      \
    f16x8 a0 = *(const f16x8*)(Arow0 + f * 32);                                          \
    f16x8 a1 = *(const f16x8*)(Arow1 + f * 32);                                          \
    acc[0][0] = __builtin_amdgcn_mfma_f32_16x16x32_f16(a0, breg0[f], acc[0][0], 0, 0, 0);\
    acc[0][1] = __builtin_amdgcn_mfma_f32_16x16x32_f16(a0, breg1[f], acc[0][1], 0, 0, 0);\
    acc[1][0] = __builtin_amdgcn_mfma_f32_16x16x32_f16(a1, breg0[f], acc[1][0], 0, 0, 0);\
    acc[1][1] = __builtin_amdgcn_mfma_f32_16x16x32_f16(a1, breg1[f], acc[1][1], 0, 0, 0);\
  }

__global__ __launch_bounds__(512, 2) void persist_kernel(
    const f16* __restrict__ x0, const f16* __restrict__ w0i,
    const f16* __restrict__ w0h, const f16* __restrict__ w1i,
    const f16* __restrict__ w1h, const float* __restrict__ b0s,
    const float* __restrict__ b1s, float* __restrict__ xg0,
    float* __restrict__ xg1, f16* __restrict__ h0r, f16* __restrict__ h1r,
    unsigned* flags) {
  __shared__ float red[16 * 64 * 4];  // 16 KB K-half reduction exchange
  __shared__ float pre[64 * 68];      // 17.4 KB preact exchange (rec)
  __shared__ float cst[64 * 16];      // 4 KB cell state (rec)

  const int stage = blockIdx.x >> 6;
  const int slice = blockIdx.x & 63;
  const int tid = threadIdx.x;
  const int lane = tid & 63;
  const int wave = tid >> 6;
  const int kh = wave >> 2, wq = wave & 3;
  const int wm = wq >> 1, wn = wq & 1;
  const int lr = lane & 15, lk = lane >> 4;
  const int j0 = slice * 16;
  const bool isrec = (stage <= 1);
  const int K = (stage == 3) ? EMB_ : HID_;
  const int nks = (stage == 3) ? 8 : 16;
  const int khoff = kh * (K >> 1);

  // ---- load this block's weight slice into registers (once) ----
  f16x8 breg0[16], breg1[16];
  {
    const f16* Wg = (stage == 0) ? w0h : (stage == 1) ? w1h : (stage == 2) ? w1i : w0i;
    int r0 = wn * 32 + lr, r1 = r0 + 16;
    size_t g0 = isrec ? (size_t)((r0 >> 4) * HID_ + j0 + (r0 & 15)) : (size_t)(slice * 64 + r0);
    size_t g1 = isrec ? (size_t)((r1 >> 4) * HID_ + j0 + (r1 & 15)) : (size_t)(slice * 64 + r1);
    const f16* p0 = Wg + g0 * K + khoff + lk * 8;
    const f16* p1 = Wg + g1 * K + khoff + lk * 8;
#pragma unroll
    for (int f = 0; f < 16; ++f)
      if (f < nks) {
        breg0[f] = *(const f16x8*)(p0 + f * 32);
        breg1[f] = *(const f16x8*)(p1 + f * 32);
      }
  }
  for (int i = tid; i < 1024; i += 512) cst[i] = 0.f;
  __syncthreads();

  for (int s = 0; s < T_ + 3; ++s) {
    bool active;
    const f16* A = nullptr;
    if (stage == 0) { active = (s >= 1 && s <= 256); if (active) A = h0r + (size_t)(s - 1) * BH; }
    else if (stage == 1) { active = (s >= 3); if (active) A = h1r + (size_t)(s - 3) * BH; }
    else if (stage == 2) { active = (s >= 2 && s <= 257); if (active) A = h0r + (size_t)(s - 1) * BH; }
    else { active = (s <= 255); if (active) A = x0 + (size_t)s * (B_ * EMB_); }

    if (active) {
      f32x4 acc[2][2] = {};
      const f16* Arow0 = A + (size_t)(wm * 32 + lr) * K + khoff + lk * 8;
      const f16* Arow1 = Arow0 + (size_t)16 * K;
      if (nks == 16) { KLOOP(16) } else { KLOOP(8) }

      // ---- K-half reduction: upper waves publish, lower waves accumulate ----
      if (kh) {
#pragma unroll
        for (int a16 = 0; a16 < 2; ++a16)
#pragma unroll
          for (int b16 = 0; b16 < 2; ++b16) {
            int fi = wq * 4 + a16 * 2 + b16;
            *(f32x4*)(red + (fi * 64 + lane) * 4) = acc[a16][b16];
          }
      }
      __syncthreads();  // S1
      if (!kh) {
#pragma unroll
        for (int a16 = 0; a16 < 2; ++a16)
#pragma unroll
          for (int b16 = 0; b16 < 2; ++b16) {
            int fi = wq * 4 + a16 * 2 + b16;
            acc[a16][b16] += *(const f32x4*)(red + (fi * 64 + lane) * 4);
          }
      }

      if (!isrec) {
        if (!kh) {
          float* outp = (stage == 2) ? xg1 + (size_t)((s - 2) & 1) * BG4
                                     : xg0 + (size_t)(s & 1) * BG4;
          const float* bsp = (stage == 2) ? b1s : b0s;
#pragma unroll
          for (int a16 = 0; a16 < 2; ++a16)
#pragma unroll
            for (int b16 = 0; b16 < 2; ++b16) {
              int n = slice * 64 + wn * 32 + b16 * 16 + lr;
              float bias = bsp[n];
              int bb = wm * 32 + a16 * 16 + lk * 4;
#pragma unroll
              for (int rg = 0; rg < 4; ++rg)
                stg_f32(&outp[(size_t)(bb + rg) * G4_ + n], acc[a16][b16][rg] + bias);
            }
        }
      } else {
        if (!kh) {
#pragma unroll
          for (int a16 = 0; a16 < 2; ++a16)
#pragma unroll
            for (int b16 = 0; b16 < 2; ++b16) {
              int nl = wn * 32 + b16 * 16 + lr;   // gate-row (gate*16+unit)
              int bl = wm * 32 + a16 * 16 + lk * 4;
              *(f32x4*)(pre + nl * 68 + bl) = acc[a16][b16];
            }
        }
        __syncthreads();  // S2
        // ---- LSTM elementwise: 512 threads x 1 pair (b, 2 units) ----
        {
          const float* xg = (stage == 0) ? xg0 + (size_t)((s - 1) & 1) * BG4
                                         : xg1 + (size_t)((s - 3) & 1) * BG4;
          f16* hout = (stage == 0) ? h0r + (size_t)s * BH
                                   : h1r + (size_t)(s - 2) * BH;
          int u2 = tid & 7, b = tid >> 3;
          int j = j0 + u2 * 2;
          unsigned long long gv[4];
#pragma unroll
          for (int g = 0; g < 4; ++g)
            gv[g] = ldg_u64(&xg[(size_t)b * G4_ + g * HID_ + j]);
          f16x2 hv;
#pragma unroll
          for (int e = 0; e < 2; ++e) {
            unsigned xi = (unsigned)(gv[0] >> (32 * e));
            unsigned xf = (unsigned)(gv[1] >> (32 * e));
            unsigned xg_ = (unsigned)(gv[2] >> (32 * e));
            unsigned xo = (unsigned)(gv[3] >> (32 * e));
            int r = u2 * 2 + e;
            float pi = pre[(0 * 16 + r) * 68 + b] + __builtin_bit_cast(float, xi);
            float pf = pre[(1 * 16 + r) * 68 + b] + __builtin_bit_cast(float, xf);
            float pg = pre[(2 * 16 + r) * 68 + b] + __builtin_bit_cast(float, xg_);
            float po = pre[(3 * 16 + r) * 68 + b] + __builtin_bit_cast(float, xo);
            float ig = sigm(pi), fg = sigm(pf), gg = tanhf(pg), og = sigm(po);
            float cn = fg * cst[b * 16 + r] + ig * gg;
            cst[b * 16 + r] = cn;
            hv[e] = (f16)(og * tanhf(cn));
          }
          stg_u32((unsigned*)(hout + (size_t)b * HID_ + j),
                  __builtin_bit_cast(unsigned, hv));
        }
      }
    }

    // ---- grid barrier: flag store + all-scan (no RMW, no fences) ----
    if (s < T_ + 2) {
      asm volatile("s_waitcnt vmcnt(0)" ::: "memory");
      __syncthreads();  // S3: every wave's stores drained
      if (tid == 0) stg_u32(&flags[blockIdx.x], (unsigned)(s + 1));
      if (wave == 0) {
        const unsigned tgt = (unsigned)(s + 1);
        const unsigned long long* fp = (const unsigned long long*)flags;
        int iters = 0;
        for (;;) {
          unsigned long long a = ldg_u64(&fp[lane * 2]);
          unsigned long long b = ldg_u64(&fp[lane * 2 + 1]);
          bool ok = ((unsigned)a >= tgt) && ((unsigned)(a >> 32) >= tgt) &&
                    ((unsigned)b >= tgt) && ((unsigned)(b >> 32) >= tgt);
          if (__all(ok)) break;
          if (++iters > 1000000) break;  // safety valve: degrade, don't hang
          __builtin_amdgcn_s_sleep(2);
        }
      }
      __syncthreads();  // S4
    }
  }
}

// ---------------- FC kernel: out = h1_last @ fc_w^T + fc_b ----------------
__global__ __launch_bounds__(256) void fc_kernel(const f16* __restrict__ A,
                                                 const float* __restrict__ fcw,
                                                 const float* __restrict__ fcb,
                                                 float* __restrict__ out) {
  const int n0 = blockIdx.x * 64;
  __shared__ char smem[18432];
  f16* As = (f16*)smem;
  f16* Bs = (f16*)(smem + 9216);
  const int tid = threadIdx.x;
  const int lane = tid & 63, wave = tid >> 6;
  const int wm = wave & 1, wn = wave >> 1;
  const int lr = lane & 15, lk = lane >> 4;
  f32x4 acc[2][2] = {};

  for (int kt = 0; kt < HID_ / 64; ++kt) {
    const int k0 = kt * 64;
    __syncthreads();
#pragma unroll
    for (int i = 0; i < 2; ++i) {
      int id = tid + 256 * i;
      int r = id >> 3, c8 = id & 7;
      uint4 av = *(const uint4*)(A + (size_t)r * HID_ + k0 + c8 * 8);
      *(uint4*)(As + r * 72 + c8 * 8) = av;
    }
#pragma unroll
    for (int i = 0; i < 4; ++i) {
      int id = tid + 256 * i;
      int r = id >> 4, c4 = id & 15;
      float4 v = *(const float4*)(fcw + (size_t)(n0 + r) * HID_ + k0 + c4 * 4);
      f16x4 o = {(f16)v.x, (f16)v.y, (f16)v.z, (f16)v.w};
      *(f16x4*)(Bs + r * 72 + c4 * 4) = o;
    }
    __syncthreads();
#pragma unroll
    for (int ks = 0; ks < 2; ++ks) {
      f16x8 a0 = *(const f16x8*)(As + (wm * 32 + lr) * 72 + ks * 32 + lk * 8);
      f16x8 a1 = *(const f16x8*)(As + (wm * 32 + 16 + lr) * 72 + ks * 32 + lk * 8);
      f16x8 b0 = *(const f16x8*)(Bs + (wn * 32 + lr) * 72 + ks * 32 + lk * 8);
      f16x8 b1 = *(const f16x8*)(Bs + (wn * 32 + 16 + lr) * 72 + ks * 32 + lk * 8);
      acc[0][0] = __builtin_amdgcn_mfma_f32_16x16x32_f16(a0, b0, acc[0][0], 0, 0, 0);
      acc[0][1] = __builtin_amdgcn_mfma_f32_16x16x32_f16(a0, b1, acc[0][1], 0, 0, 0);
      acc[1][0] = __builtin_amdgcn_mfma_f32_16x16x32_f16(a1, b0, acc[1][0], 0, 0, 0);
      acc[1][1] = __builtin_amdgcn_mfma_f32_16x16x32_f16(a1, b1, acc[1][1], 0, 0, 0);
    }
  }

#pragma unroll
  for (int mf = 0; mf < 2; ++mf)
#pragma unroll
    for (int nf = 0; nf < 2; ++nf) {
      int n = n0 + wn * 32 + nf * 16 + lr;
      float bias = fcb[n];
      int bbase = wm * 32 + mf * 16 + lk * 4;
#pragma unroll
      for (int rg = 0; rg < 4; ++rg)
        out[(size_t)(bbase + rg) * NCLS_ + n] = acc[mf][nf][rg] + bias;
    }
}

// ---------------- launch ----------------

extern "C" void kernel_launch(void* const* d_in, const int* in_sizes, int n_in,
                              void* d_out, int out_size, void* d_ws,
                              size_t ws_size, hipStream_t stream) {
  const int* tokens = (const int*)d_in[0];
  const float* emb = (const float*)d_in[1];
  const float* W_ih0 = (const float*)d_in[2];
  const float* W_hh0 = (const float*)d_in[3];
  const float* b_ih0 = (const float*)d_in[4];
  const float* b_hh0 = (const float*)d_in[5];
  const float* W_ih1 = (const float*)d_in[6];
  const float* W_hh1 = (const float*)d_in[7];
  const float* b_ih1 = (const float*)d_in[8];
  const float* b_hh1 = (const float*)d_in[9];
  const float* fc_w = (const float*)d_in[10];
  const float* fc_b = (const float*)d_in[11];
  float* out = (float*)d_out;

  char* ws = (char*)d_ws;
  size_t off = 0;
  auto carve = [&](size_t bytes) -> char* {
    char* p = ws + off;
    off += (bytes + 255) & ~(size_t)255;
    return p;
  };
  f16* w0i = (f16*)carve((size_t)G4_ * EMB_ * 2);
  f16* w0h = (f16*)carve((size_t)G4_ * HID_ * 2);
  f16* w1i = (f16*)carve((size_t)G4_ * HID_ * 2);
  f16* w1h = (f16*)carve((size_t)G4_ * HID_ * 2);
  f16* x0 = (f16*)carve((size_t)T_ * B_ * EMB_ * 2);
  float* b0s = (float*)carve(G4_ * 4);
  float* b1s = (float*)carve(G4_ * 4);
  float* xg0 = (float*)carve(2ull * BG4 * 4);
  float* xg1 = (float*)carve(2ull * BG4 * 4);
  f16* h0r = (f16*)carve(257ull * BH * 2);  // single-assignment ring, slot t+1 = h[t]
  f16* h1r = (f16*)carve(257ull * BH * 2);
  unsigned* flags = (unsigned*)carve(256 * 4);

  // zero: barrier flags + h[-1] slots (deterministic per call)
  hipMemsetAsync(flags, 0, 256 * 4, stream);
  hipMemsetAsync(h0r, 0, (size_t)BH * 2, stream);
  hipMemsetAsync(h1r, 0, (size_t)BH * 2, stream);

  cvt_kernel<<<(G4_ * EMB_ / 4 + 255) / 256, 256, 0, stream>>>(W_ih0, w0i, G4_ * EMB_ / 4);
  cvt_kernel<<<(G4_ * HID_ / 4 + 255) / 256, 256, 0, stream>>>(W_hh0, w0h, G4_ * HID_ / 4);
  cvt_kernel<<<(G4_ * HID_ / 4 + 255) / 256, 256, 0, stream>>>(W_ih1, w1i, G4_ * HID_ / 4);
  cvt_kernel<<<(G4_ * HID_ / 4 + 255) / 256, 256, 0, stream>>>(W_hh1, w1h, G4_ * HID_ / 4);
  bsum_kernel<<<(G4_ + 255) / 256, 256, 0, stream>>>(b_ih0, b_hh0, b0s, b_ih1, b_hh1, b1s);
  gather_kernel<<<T_ * B_, 128, 0, stream>>>(tokens, emb, x0);

  persist_kernel<<<256, 512, 0, stream>>>(x0, w0i, w0h, w1i, w1h, b0s, b1s,
                                          xg0, xg1, h0r, h1r, flags);

  fc_kernel<<<NCLS_ / 64, 256, 0, stream>>>(h1r + 256ull * BH, fc_w, fc_b, out);
}